// Round 6
// baseline (4281.574 us; speedup 1.0000x reference)
//
#include <hip/hip_runtime.h>
#include <hip/hip_bf16.h>

typedef unsigned short u16;
typedef __attribute__((ext_vector_type(8))) short short8v;

__device__ inline u16 f2b(float f) {
    __hip_bfloat16 h = __float2bfloat16(f);
    u16 u; __builtin_memcpy(&u, &h, 2); return u;
}
__device__ inline float b2f(u16 u) {
    __hip_bfloat16 h; __builtin_memcpy(&h, &u, 2); return __bfloat162float(h);
}

// ---------------------------------------------------------------------------
// Naive tiled GEMM: C[m][n] = sum_k A[m][k] * B[n][k] + bias[n]
// A: fp32 (ABF=0) or bf16 (ABF=1). B, bias fp32. fp32 accumulation.
// OF32=1 -> C fp32 (the real d_out dtype); OF32=0 -> C bf16 (intermediates).
// block (16,16); 16x16 LDS tiles; correctness-first probe (round-5 lineage).
// ---------------------------------------------------------------------------
template<int ABF, int OF32>
__global__ __launch_bounds__(256) void naive_gemm(
    const void* __restrict__ Ap, const float* __restrict__ Bw,
    const float* __restrict__ bias, void* __restrict__ Cp,
    int M, int N, int K)
{
    __shared__ float As[16][17];
    __shared__ float Bs[16][17];
    const int tx = threadIdx.x, ty = threadIdx.y;      // tx -> n, ty -> m
    const int n0 = blockIdx.x * 16, m0 = blockIdx.y * 16;
    const int n = n0 + tx, m = m0 + ty;

    float acc = 0.f;
    for (int k0 = 0; k0 < K; k0 += 16) {
        if (ABF) As[ty][tx] = b2f(((const u16*)Ap)[(size_t)(m0 + ty) * K + k0 + tx]);
        else     As[ty][tx] = ((const float*)Ap)[(size_t)(m0 + ty) * K + k0 + tx];
        Bs[ty][tx] = Bw[(size_t)(n0 + ty) * K + k0 + tx];
        __syncthreads();
        #pragma unroll
        for (int kk = 0; kk < 16; ++kk)
            acc += As[ty][kk] * Bs[tx][kk];
        __syncthreads();
    }
    const float r = acc + bias[n];
    if (OF32) ((float*)Cp)[(size_t)m * N + n] = r;
    else      ((u16*)Cp)[(size_t)m * N + n]   = f2b(r);
}

// ---------------------------------------------------------------------------
// Naive flash attention (causal): one thread per q-row per head. fp32 online
// softmax over bf16 Q/KV. Unchanged from round 5.
// Q [b][n][1024] bf16 (head hi at cols hi*64); KV [b][n][2048] bf16
// (K cols 0..1023, V cols 1024..2047). AO aliases Q safely (each thread reads
// only its own Q row/head before writing it; other blocks touch disjoint
// row/col regions).
// ---------------------------------------------------------------------------
__global__ __launch_bounds__(256) void naive_flash(
    const u16* __restrict__ Q, const u16* __restrict__ KV, u16* __restrict__ AO)
{
    const int q  = blockIdx.x * 256 + threadIdx.x;   // 0..2047
    const int hi = blockIdx.y, bi = blockIdx.z;

    const u16* qp = Q + ((size_t)(bi * 2048 + q)) * 1024 + hi * 64;
    float qv[64];
    #pragma unroll
    for (int c = 0; c < 8; ++c) {
        const short8v v = *(const short8v*)(qp + c * 8);
        #pragma unroll
        for (int e = 0; e < 8; ++e) qv[c * 8 + e] = b2f((u16)v[e]) * 0.125f;  // fold scale
    }

    float o[64];
    #pragma unroll
    for (int d = 0; d < 64; ++d) o[d] = 0.f;
    float m = -1e30f, l = 0.f;

    const u16* kvb = KV + (size_t)bi * 2048 * 2048 + hi * 64;
    for (int j = 0; j <= q; ++j) {
        const u16* kp = kvb + (size_t)j * 2048;
        float s = 0.f;
        #pragma unroll
        for (int c = 0; c < 8; ++c) {
            const short8v v = *(const short8v*)(kp + c * 8);
            #pragma unroll
            for (int e = 0; e < 8; ++e) s += qv[c * 8 + e] * b2f((u16)v[e]);
        }
        const float mnew = fmaxf(m, s);
        const float cc = __expf(m - mnew);
        const float p  = __expf(s - mnew);
        l = l * cc + p;
        const u16* vp = kp + 1024;
        #pragma unroll
        for (int c = 0; c < 8; ++c) {
            const short8v v = *(const short8v*)(vp + c * 8);
            #pragma unroll
            for (int e = 0; e < 8; ++e) o[c * 8 + e] = o[c * 8 + e] * cc + p * b2f((u16)v[e]);
        }
        m = mnew;
    }

    u16* op = AO + ((size_t)(bi * 2048 + q)) * 1024 + hi * 64;
    const float inv = 1.f / l;
    #pragma unroll
    for (int c = 0; c < 8; ++c) {
        short8v v;
        #pragma unroll
        for (int e = 0; e < 8; ++e) v[e] = (short)f2b(o[c * 8 + e] * inv);
        *(short8v*)(op + c * 8) = v;
    }
}

// ---------------------------------------------------------------------------
extern "C" void kernel_launch(void* const* d_in, const int* in_sizes, int n_in,
                              void* d_out, int out_size, void* d_ws, size_t ws_size,
                              hipStream_t stream) {
    const float* x   = (const float*)d_in[0];
    const float* Wq  = (const float*)d_in[1];
    const float* bq  = (const float*)d_in[2];
    const float* Wkv = (const float*)d_in[3];
    const float* bkv = (const float*)d_in[4];
    const float* Wo  = (const float*)d_in[5];
    const float* bo  = (const float*)d_in[6];
    float* out = (float*)d_out;               // fp32 output — THE round-6 change

    u16* Qb  = (u16*)d_ws;                    // 4096 x 1024 bf16 (reused as AO)
    u16* KVb = Qb + (size_t)4096 * 1024;      // 4096 x 2048 bf16   (ws >= 42MB proven)

    dim3 blk(16, 16);
    naive_gemm<0, 0><<<dim3( 64, 256), blk, 0, stream>>>(x,  Wq,  bq,  Qb,  4096, 1024, 1024);
    naive_gemm<0, 0><<<dim3(128, 256), blk, 0, stream>>>(x,  Wkv, bkv, KVb, 4096, 2048, 1024);
    naive_flash<<<dim3(8, 16, 2), dim3(256), 0, stream>>>(Qb, KVb, Qb);
    naive_gemm<1, 1><<<dim3( 64, 256), blk, 0, stream>>>(Qb, Wo,  bo,  out, 4096, 1024, 1024);
}

// Round 7
// 301.537 us; speedup vs baseline: 14.1991x; 14.1991x over previous
//
#include <hip/hip_runtime.h>
#include <hip/hip_bf16.h>

typedef unsigned short u16;
typedef __attribute__((ext_vector_type(8))) short short8v;   // 8 bf16 = 16B
typedef __attribute__((ext_vector_type(4))) float f32x4;

__device__ inline u16 f2b(float f) {
    __hip_bfloat16 h = __float2bfloat16(f);
    u16 u; __builtin_memcpy(&u, &h, 2); return u;
}
__device__ inline float b2f(u16 u) {
    __hip_bfloat16 h; __builtin_memcpy(&h, &u, 2); return __bfloat162float(h);
}
// load 8 contiguous fp32, round to 8 bf16
__device__ inline short8v cvt8(const float* p) {
    const f32x4 a = *(const f32x4*)p;
    const f32x4 b = *(const f32x4*)(p + 4);
    short8v s;
    #pragma unroll
    for (int e = 0; e < 4; ++e) { s[e] = (short)f2b(a[e]); s[4 + e] = (short)f2b(b[e]); }
    return s;
}

// ---------------------------------------------------------------------------
// GEMM: C[m][n] = sum_k A[m][k] * B[n][k] + bias[n]   (fp32 accum)
// A: fp32 (ABF=0) or bf16 (ABF=1); B,bias fp32; C: bf16 (OF32=0) / fp32 (=1).
// 128x128 tile, BK=32, 256 thr (4 waves 2x2, 64x64 each, 4x4 frags).
// Reg-staged LDS, padded stride 40 u16.
// ---------------------------------------------------------------------------
template<int ABF, int OF32>
__global__ __launch_bounds__(256, 2) void gemm_bt_bias(
    const void* __restrict__ Ap, const float* __restrict__ Bw,
    const float* __restrict__ bias, void* __restrict__ Cp,
    int M, int N, int K)
{
    __shared__ __align__(16) u16 As[128 * 40];
    __shared__ __align__(16) u16 Bs[128 * 40];
    const int tid  = threadIdx.x;
    const int wave = tid >> 6, lane = tid & 63;
    const int l15  = lane & 15, l4 = lane >> 4;
    const int row0 = blockIdx.x * 128, col0 = blockIdx.y * 128;
    const int wm = (wave >> 1) * 64, wn = (wave & 1) * 64;

    f32x4 acc[4][4];
    #pragma unroll
    for (int i = 0; i < 4; ++i)
        #pragma unroll
        for (int j = 0; j < 4; ++j) acc[i][j] = (f32x4)0.f;

    const int sr = tid >> 2, sc = tid & 3;   // stage: row(0..63), 16B-chunk(0..3)

    for (int kt = 0; kt < K; kt += 32) {
        short8v va[2], vb[2];
        #pragma unroll
        for (int it = 0; it < 2; ++it) {
            const int r = sr + it * 64;
            if (ABF) va[it] = *(const short8v*)((const u16*)Ap + (size_t)(row0 + r) * K + kt + sc * 8);
            else     va[it] = cvt8((const float*)Ap + (size_t)(row0 + r) * K + kt + sc * 8);
            vb[it] = cvt8(Bw + (size_t)(col0 + r) * K + kt + sc * 8);
        }
        __syncthreads();                      // prev tile's LDS reads complete
        #pragma unroll
        for (int it = 0; it < 2; ++it) {
            const int r = sr + it * 64;
            *(short8v*)&As[r * 40 + sc * 8] = va[it];
            *(short8v*)&Bs[r * 40 + sc * 8] = vb[it];
        }
        __syncthreads();

        short8v af[4], bf[4];
        #pragma unroll
        for (int i = 0; i < 4; ++i) {
            af[i] = *(const short8v*)&As[(wm + i * 16 + l15) * 40 + l4 * 8];
            bf[i] = *(const short8v*)&Bs[(wn + i * 16 + l15) * 40 + l4 * 8];
        }
        #pragma unroll
        for (int i = 0; i < 4; ++i)
            #pragma unroll
            for (int j = 0; j < 4; ++j)
                acc[i][j] = __builtin_amdgcn_mfma_f32_16x16x32_bf16(af[i], bf[j], acc[i][j], 0, 0, 0);
    }

    // epilogue: D layout col=lane&15, row=(lane>>4)*4+reg
    #pragma unroll
    for (int i = 0; i < 4; ++i) {
        const int r = row0 + wm + i * 16 + l4 * 4;
        #pragma unroll
        for (int j = 0; j < 4; ++j) {
            const int c = col0 + wn + j * 16 + l15;
            const float bv = bias[c];
            #pragma unroll
            for (int reg = 0; reg < 4; ++reg) {
                const float rv = acc[i][j][reg] + bv;
                if (OF32) ((float*)Cp)[(size_t)(r + reg) * N + c] = rv;
                else      ((u16*)Cp)[(size_t)(r + reg) * N + c]   = f2b(rv);
            }
        }
    }
}

// ---------------------------------------------------------------------------
// MFMA flash attention (causal). Q [b][n][1024] bf16 (head hi cols hi*64..);
// KV [b][n][2048] bf16: K cols 0..1023, V cols 1024..2047.
// 256 threads = 4 waves; 64 q-rows/block (16/wave); KV tile 32.
// AO may alias Q: each block reads only the Q region it writes, before writing.
// ---------------------------------------------------------------------------
#define ATT_N 2048
#define ATT_D 1024
#define ATT_HD 64

__global__ __launch_bounds__(256, 2) void flash_attn_kernel(
    const u16* __restrict__ Q, const u16* __restrict__ KV, u16* __restrict__ AO)
{
    const int tid  = threadIdx.x;
    const int wave = tid >> 6, lane = tid & 63;
    const int l15  = lane & 15, l4 = lane >> 4;
    const int qt = blockIdx.x, hi = blockIdx.y, bi = blockIdx.z;
    const int q0  = qt * 64;
    const int qr0 = q0 + wave * 16;

    __shared__ __align__(16) u16 Ks[32 * 72];        // K tile, padded
    __shared__ __align__(16) u16 Vt[64 * 40];        // transposed V, padded
    __shared__ __align__(16) u16 Ps[4][16 * 40];     // per-wave P, padded

    // Q fragments (A operand): lane holds row l15, k = l4*8 + [0..7]
    const u16* qp = Q + ((size_t)(bi * ATT_N + qr0 + l15)) * ATT_D + hi * ATT_HD;
    const short8v aq0 = *(const short8v*)(qp + l4 * 8);
    const short8v aq1 = *(const short8v*)(qp + 32 + l4 * 8);

    float mrow[4], lrow[4];
    f32x4 oacc[4];
    #pragma unroll
    for (int r = 0; r < 4; ++r) { mrow[r] = -1e30f; lrow[r] = 0.f; oacc[r] = (f32x4)0.f; }

    const int nt = (q0 + 64) / 32;
    const int krow = tid >> 3, kch = tid & 7;
    const size_t kv_base = (size_t)bi * ATT_N * 2048;

    for (int t = 0; t < nt; ++t) {
        const int kv0 = t * 32;
        const u16* grow = KV + kv_base + (size_t)(kv0 + krow) * 2048 + hi * ATT_HD;
        const short8v kvv = *(const short8v*)(grow + kch * 8);
        const short8v vvv = *(const short8v*)(grow + 1024 + kch * 8);
        __syncthreads();                      // prev tile compute done
        *(short8v*)&Ks[krow * 72 + kch * 8] = kvv;
        #pragma unroll
        for (int e = 0; e < 8; ++e) Vt[(kch * 8 + e) * 40 + krow] = (u16)vvv[e];
        __syncthreads();

        if (kv0 <= qr0 + 15) {   // wave-uniform: skip fully-masked tiles
            // S = Q K^T : 16 q x 32 kv; D row=l4*4+reg (q), col=l15 (kv)
            f32x4 s[2] = {(f32x4)0.f, (f32x4)0.f};
            #pragma unroll
            for (int tt = 0; tt < 2; ++tt) {
                const int rb = tt * 16 + l15;
                const short8v bk0 = *(const short8v*)&Ks[rb * 72 + l4 * 8];
                const short8v bk1 = *(const short8v*)&Ks[rb * 72 + (4 + l4) * 8];
                s[tt] = __builtin_amdgcn_mfma_f32_16x16x32_bf16(aq0, bk0, s[tt], 0, 0, 0);
                s[tt] = __builtin_amdgcn_mfma_f32_16x16x32_bf16(aq1, bk1, s[tt], 0, 0, 0);
            }
            // scale + causal mask
            float pv[2][4];
            #pragma unroll
            for (int tt = 0; tt < 2; ++tt)
                #pragma unroll
                for (int r = 0; r < 4; ++r) {
                    const int qg = qr0 + l4 * 4 + r;
                    const int kg = kv0 + tt * 16 + l15;
                    const float sv = s[tt][r] * 0.125f;
                    pv[tt][r] = (kg <= qg) ? sv : -1e30f;
                }
            // online softmax: reduce over l15 (xor 1,2,4,8 keeps l4 groups)
            #pragma unroll
            for (int r = 0; r < 4; ++r) {
                float v = fmaxf(pv[0][r], pv[1][r]);
                #pragma unroll
                for (int off = 1; off < 16; off <<= 1)
                    v = fmaxf(v, __shfl_xor(v, off, 64));
                const float mnew = fmaxf(mrow[r], v);
                const float sf = __expf(mrow[r] - mnew);
                mrow[r] = mnew;
                lrow[r] *= sf;
                #pragma unroll
                for (int j = 0; j < 4; ++j) oacc[j][r] *= sf;
                const float p0 = __expf(pv[0][r] - mnew);
                const float p1 = __expf(pv[1][r] - mnew);
                pv[0][r] = p0; pv[1][r] = p1;
                float sum = p0 + p1;
                #pragma unroll
                for (int off = 1; off < 16; off <<= 1)
                    sum += __shfl_xor(sum, off, 64);
                lrow[r] += sum;
            }
            // P -> LDS (bf16), read back as A fragment
            u16* Pw = &Ps[wave][0];
            #pragma unroll
            for (int tt = 0; tt < 2; ++tt)
                #pragma unroll
                for (int r = 0; r < 4; ++r)
                    Pw[(l4 * 4 + r) * 40 + tt * 16 + l15] = f2b(pv[tt][r]);
            const short8v ap = *(const short8v*)&Pw[l15 * 40 + l4 * 8];
            #pragma unroll
            for (int j = 0; j < 4; ++j) {
                const short8v bv = *(const short8v*)&Vt[(j * 16 + l15) * 40 + l4 * 8];
                oacc[j] = __builtin_amdgcn_mfma_f32_16x16x32_bf16(ap, bv, oacc[j], 0, 0, 0);
            }
        }
    }

    // epilogue: divide by l, store bf16
    u16* op = AO + ((size_t)(bi * ATT_N + qr0)) * ATT_D + hi * ATT_HD;
    #pragma unroll
    for (int j = 0; j < 4; ++j)
        #pragma unroll
        for (int r = 0; r < 4; ++r)
            op[(size_t)(l4 * 4 + r) * ATT_D + j * 16 + l15] = f2b(oacc[j][r] / lrow[r]);
}

// ---------------------------------------------------------------------------
extern "C" void kernel_launch(void* const* d_in, const int* in_sizes, int n_in,
                              void* d_out, int out_size, void* d_ws, size_t ws_size,
                              hipStream_t stream) {
    const float* x   = (const float*)d_in[0];
    const float* Wq  = (const float*)d_in[1];
    const float* bq  = (const float*)d_in[2];
    const float* Wkv = (const float*)d_in[3];
    const float* bkv = (const float*)d_in[4];
    const float* Wo  = (const float*)d_in[5];
    const float* bo  = (const float*)d_in[6];
    float* out = (float*)d_out;               // fp32 output (round-6 proven)

    u16* Qb  = (u16*)d_ws;                    // 4096 x 1024 bf16 (reused as AO)
    u16* KVb = Qb + (size_t)4096 * 1024;      // 4096 x 2048 bf16

    dim3 blk(256);
    gemm_bt_bias<0, 0><<<dim3(32,  8), blk, 0, stream>>>(x,  Wq,  bq,  Qb,  4096, 1024, 1024);
    gemm_bt_bias<0, 0><<<dim3(32, 16), blk, 0, stream>>>(x,  Wkv, bkv, KVb, 4096, 2048, 1024);
    flash_attn_kernel<<<dim3(32, 16, 2), blk, 0, stream>>>(Qb, KVb, Qb);
    gemm_bt_bias<1, 1><<<dim3(32,  8), blk, 0, stream>>>(Qb, Wo,  bo,  out, 4096, 1024, 1024);
}

// Round 9
// 177.954 us; speedup vs baseline: 24.0600x; 1.6945x over previous
//
#include <hip/hip_runtime.h>
#include <hip/hip_bf16.h>

typedef unsigned short u16;
typedef __attribute__((ext_vector_type(8))) short short8v;   // 8 bf16 = 16B
typedef __attribute__((ext_vector_type(4))) float f32x4;

__device__ inline u16 f2b(float f) {
    __hip_bfloat16 h = __float2bfloat16(f);
    u16 u; __builtin_memcpy(&u, &h, 2); return u;
}
__device__ inline float b2f(u16 u) {
    __hip_bfloat16 h; __builtin_memcpy(&h, &u, 2); return __bfloat162float(h);
}
// load 8 contiguous fp32, round to 8 bf16
__device__ inline short8v cvt8(const float* p) {
    const f32x4 a = *(const f32x4*)p;
    const f32x4 b = *(const f32x4*)(p + 4);
    short8v s;
    #pragma unroll
    for (int e = 0; e < 4; ++e) { s[e] = (short)f2b(a[e]); s[4 + e] = (short)f2b(b[e]); }
    return s;
}

// ---------------------------------------------------------------------------
// GEMM (round-7 proven): C = A @ B^T + bias, fp32 accum.
// ---------------------------------------------------------------------------
template<int ABF, int OF32>
__global__ __launch_bounds__(256, 2) void gemm_bt_bias(
    const void* __restrict__ Ap, const float* __restrict__ Bw,
    const float* __restrict__ bias, void* __restrict__ Cp,
    int M, int N, int K)
{
    __shared__ __align__(16) u16 As[128 * 40];
    __shared__ __align__(16) u16 Bs[128 * 40];
    const int tid  = threadIdx.x;
    const int wave = tid >> 6, lane = tid & 63;
    const int l15  = lane & 15, l4 = lane >> 4;
    const int row0 = blockIdx.x * 128, col0 = blockIdx.y * 128;
    const int wm = (wave >> 1) * 64, wn = (wave & 1) * 64;

    f32x4 acc[4][4];
    #pragma unroll
    for (int i = 0; i < 4; ++i)
        #pragma unroll
        for (int j = 0; j < 4; ++j) acc[i][j] = (f32x4)0.f;

    const int sr = tid >> 2, sc = tid & 3;

    for (int kt = 0; kt < K; kt += 32) {
        short8v va[2], vb[2];
        #pragma unroll
        for (int it = 0; it < 2; ++it) {
            const int r = sr + it * 64;
            if (ABF) va[it] = *(const short8v*)((const u16*)Ap + (size_t)(row0 + r) * K + kt + sc * 8);
            else     va[it] = cvt8((const float*)Ap + (size_t)(row0 + r) * K + kt + sc * 8);
            vb[it] = cvt8(Bw + (size_t)(col0 + r) * K + kt + sc * 8);
        }
        __syncthreads();
        #pragma unroll
        for (int it = 0; it < 2; ++it) {
            const int r = sr + it * 64;
            *(short8v*)&As[r * 40 + sc * 8] = va[it];
            *(short8v*)&Bs[r * 40 + sc * 8] = vb[it];
        }
        __syncthreads();

        short8v af[4], bf[4];
        #pragma unroll
        for (int i = 0; i < 4; ++i) {
            af[i] = *(const short8v*)&As[(wm + i * 16 + l15) * 40 + l4 * 8];
            bf[i] = *(const short8v*)&Bs[(wn + i * 16 + l15) * 40 + l4 * 8];
        }
        #pragma unroll
        for (int i = 0; i < 4; ++i)
            #pragma unroll
            for (int j = 0; j < 4; ++j)
                acc[i][j] = __builtin_amdgcn_mfma_f32_16x16x32_bf16(af[i], bf[j], acc[i][j], 0, 0, 0);
    }

    #pragma unroll
    for (int i = 0; i < 4; ++i) {
        const int r = row0 + wm + i * 16 + l4 * 4;
        #pragma unroll
        for (int j = 0; j < 4; ++j) {
            const int c = col0 + wn + j * 16 + l15;
            const float bv = bias[c];
            #pragma unroll
            for (int reg = 0; reg < 4; ++reg) {
                const float rv = acc[i][j][reg] + bv;
                if (OF32) ((float*)Cp)[(size_t)(r + reg) * N + c] = rv;
                else      ((u16*)Cp)[(size_t)(r + reg) * N + c]   = f2b(rv);
            }
        }
    }
}

// ---------------------------------------------------------------------------
// V transpose: VT[bi][hi][d][n] = V[bi][n][hi*64+d]  (V = KVb cols 1024..2047)
// ---------------------------------------------------------------------------
__global__ __launch_bounds__(256) void vtrans_kernel(
    const u16* __restrict__ KVb, u16* __restrict__ VT)
{
    const int u    = blockIdx.x * 4 + (threadIdx.x >> 6);
    const int lane = threadIdx.x & 63;
    const int nch  = u & 255;            // 256 chunks of 8 n
    const int hi   = (u >> 8) & 15;
    const int bi   = u >> 12;
    const int n0   = nch * 8;

    short8v sv;
    #pragma unroll
    for (int i = 0; i < 8; ++i)
        sv[i] = (short)KVb[((size_t)(bi * 2048 + n0 + i)) * 2048 + 1024 + hi * 64 + lane];
    *(short8v*)&VT[((size_t)((bi * 16 + hi) * 64 + lane)) * 2048 + n0] = sv;
}

// ---------------------------------------------------------------------------
// Flash attention (causal). KVBLK=64; causal-paired q-tiles (p, 31-p), 33
// tiles per block. 4 waves, 64 q-rows per q-tile (16/wave). V from VT.
// AO is a SEPARATE buffer (round-9: de-aliased for replay determinism).
// ---------------------------------------------------------------------------
#define ATT_N 2048
#define ATT_D 1024
#define ATT_HD 64

__global__ __launch_bounds__(256, 2) void flash_attn_kernel(
    const u16* __restrict__ Q, const u16* __restrict__ KV,
    const u16* __restrict__ VT, u16* __restrict__ AO)
{
    const int tid  = threadIdx.x;
    const int wave = tid >> 6, lane = tid & 63;
    const int l15  = lane & 15, l4 = lane >> 4;
    const int pidx = blockIdx.x, hi = blockIdx.y, bi = blockIdx.z;

    __shared__ __align__(16) u16 Ks[64 * 72];        // K tile  [kv][d]
    __shared__ __align__(16) u16 Vs[64 * 72];        // V^T tile [d][kv]
    __shared__ __align__(16) u16 Ps[4][16 * 72];     // per-wave P [q][kv]

    const int sr = tid >> 2, sc = tid & 3;           // stage row, 32B chunk
    const size_t kv_base = (size_t)bi * ATT_N * 2048;
    const size_t vt_base = ((size_t)(bi * 16 + hi)) * 64 * ATT_N;

    for (int ph = 0; ph < 2; ++ph) {
        const int qt  = ph ? (31 - pidx) : pidx;
        const int q0  = qt * 64;
        const int qr0 = q0 + wave * 16;

        const u16* qp = Q + ((size_t)(bi * ATT_N + qr0 + l15)) * ATT_D + hi * ATT_HD;
        const short8v aq0 = *(const short8v*)(qp + l4 * 8);
        const short8v aq1 = *(const short8v*)(qp + 32 + l4 * 8);

        float mrow[4], lrow[4];
        f32x4 oacc[4];
        #pragma unroll
        for (int r = 0; r < 4; ++r) { mrow[r] = -1e30f; lrow[r] = 0.f; oacc[r] = (f32x4)0.f; }

        const int nt = qt + 1;
        for (int t = 0; t < nt; ++t) {
            const int kv0 = t * 64;
            const u16* gk = KV + kv_base + (size_t)(kv0 + sr) * 2048 + hi * ATT_HD + sc * 16;
            const u16* gv = VT + vt_base + (size_t)sr * ATT_N + kv0 + sc * 16;
            const short8v k0 = *(const short8v*)gk;
            const short8v k1 = *(const short8v*)(gk + 8);
            const short8v v0 = *(const short8v*)gv;
            const short8v v1 = *(const short8v*)(gv + 8);
            __syncthreads();                  // prev tile LDS reads done
            *(short8v*)&Ks[sr * 72 + sc * 16]     = k0;
            *(short8v*)&Ks[sr * 72 + sc * 16 + 8] = k1;
            *(short8v*)&Vs[sr * 72 + sc * 16]     = v0;
            *(short8v*)&Vs[sr * 72 + sc * 16 + 8] = v1;
            __syncthreads();

            // S = Q K^T : 16q x 64kv; D row=l4*4+reg (q), col=l15 (kv)
            f32x4 s[4];
            #pragma unroll
            for (int tt = 0; tt < 4; ++tt) {
                s[tt] = (f32x4)0.f;
                const int rb = tt * 16 + l15;
                const short8v bk0 = *(const short8v*)&Ks[rb * 72 + l4 * 8];
                const short8v bk1 = *(const short8v*)&Ks[rb * 72 + 32 + l4 * 8];
                s[tt] = __builtin_amdgcn_mfma_f32_16x16x32_bf16(aq0, bk0, s[tt], 0, 0, 0);
                s[tt] = __builtin_amdgcn_mfma_f32_16x16x32_bf16(aq1, bk1, s[tt], 0, 0, 0);
            }
            float pv[4][4];
            #pragma unroll
            for (int tt = 0; tt < 4; ++tt)
                #pragma unroll
                for (int r = 0; r < 4; ++r) {
                    const int qg = qr0 + l4 * 4 + r;
                    const int kg = kv0 + tt * 16 + l15;
                    pv[tt][r] = (kg <= qg) ? s[tt][r] * 0.125f : -1e30f;
                }
            #pragma unroll
            for (int r = 0; r < 4; ++r) {
                float v = fmaxf(fmaxf(pv[0][r], pv[1][r]), fmaxf(pv[2][r], pv[3][r]));
                #pragma unroll
                for (int off = 1; off < 16; off <<= 1)
                    v = fmaxf(v, __shfl_xor(v, off, 64));
                const float mnew = fmaxf(mrow[r], v);
                const float sf = __expf(mrow[r] - mnew);
                mrow[r] = mnew;
                lrow[r] *= sf;
                #pragma unroll
                for (int j = 0; j < 4; ++j) oacc[j][r] *= sf;
                float sum = 0.f;
                #pragma unroll
                for (int tt = 0; tt < 4; ++tt) {
                    const float p = __expf(pv[tt][r] - mnew);
                    pv[tt][r] = p;
                    sum += p;
                }
                #pragma unroll
                for (int off = 1; off < 16; off <<= 1)
                    sum += __shfl_xor(sum, off, 64);
                lrow[r] += sum;
            }
            u16* Pw = &Ps[wave][0];
            #pragma unroll
            for (int tt = 0; tt < 4; ++tt)
                #pragma unroll
                for (int r = 0; r < 4; ++r)
                    Pw[(l4 * 4 + r) * 72 + tt * 16 + l15] = f2b(pv[tt][r]);
            const short8v ap0 = *(const short8v*)&Pw[l15 * 72 + l4 * 8];
            const short8v ap1 = *(const short8v*)&Pw[l15 * 72 + 32 + l4 * 8];
            #pragma unroll
            for (int j = 0; j < 4; ++j) {
                const int rb = j * 16 + l15;
                const short8v bv0 = *(const short8v*)&Vs[rb * 72 + l4 * 8];
                const short8v bv1 = *(const short8v*)&Vs[rb * 72 + 32 + l4 * 8];
                oacc[j] = __builtin_amdgcn_mfma_f32_16x16x32_bf16(ap0, bv0, oacc[j], 0, 0, 0);
                oacc[j] = __builtin_amdgcn_mfma_f32_16x16x32_bf16(ap1, bv1, oacc[j], 0, 0, 0);
            }
        }

        u16* op = AO + ((size_t)(bi * ATT_N + qr0)) * ATT_D + hi * ATT_HD;
        #pragma unroll
        for (int j = 0; j < 4; ++j)
            #pragma unroll
            for (int r = 0; r < 4; ++r)
                op[(size_t)(l4 * 4 + r) * ATT_D + j * 16 + l15] = f2b(oacc[j][r] / lrow[r]);
    }
}

// ---------------------------------------------------------------------------
extern "C" void kernel_launch(void* const* d_in, const int* in_sizes, int n_in,
                              void* d_out, int out_size, void* d_ws, size_t ws_size,
                              hipStream_t stream) {
    const float* x   = (const float*)d_in[0];
    const float* Wq  = (const float*)d_in[1];
    const float* bq  = (const float*)d_in[2];
    const float* Wkv = (const float*)d_in[3];
    const float* bkv = (const float*)d_in[4];
    const float* Wo  = (const float*)d_in[5];
    const float* bo  = (const float*)d_in[6];
    float* out = (float*)d_out;

    u16* Qb  = (u16*)d_ws;                    // 4096 x 1024 bf16 ( 8MB)
    u16* KVb = Qb  + (size_t)4096 * 1024;     // 4096 x 2048 bf16 (16MB)
    u16* VTb = KVb + (size_t)4096 * 2048;     // [2][16][64][2048] (8MB)
    u16* AOb = VTb + (size_t)2 * 16 * 64 * 2048; // 4096 x 1024 bf16 (8MB) — de-aliased

    dim3 blk(256);
    gemm_bt_bias<0, 0><<<dim3(32,  8), blk, 0, stream>>>(x,  Wq,  bq,  Qb,  4096, 1024, 1024);
    gemm_bt_bias<0, 0><<<dim3(32, 16), blk, 0, stream>>>(x,  Wkv, bkv, KVb, 4096, 2048, 1024);
    vtrans_kernel<<<dim3(2048), blk, 0, stream>>>(KVb, VTb);
    flash_attn_kernel<<<dim3(16, 16, 2), blk, 0, stream>>>(Qb, KVb, VTb, AOb);
    gemm_bt_bias<1, 1><<<dim3(32,  8), blk, 0, stream>>>(AOb, Wo,  bo,  out, 4096, 1024, 1024);
}